// Round 7
// baseline (865.782 us; speedup 1.0000x reference)
//
#include <hip/hip_runtime.h>
#include <hip/hip_bf16.h>
#include <cstdint>
#include <cstddef>

// Problem constants (fixed by the harness problem instance).
#define MM 8192
#define KK 4096
#define NN 12288

typedef __bf16 bf16x8 __attribute__((ext_vector_type(8)));
typedef float  f32x4  __attribute__((ext_vector_type(4)));
typedef float  f32x16 __attribute__((ext_vector_type(16)));

// fp32 -> bf16 round-to-nearest-even (finite inputs).
__device__ __forceinline__ unsigned short f2bf(float f) {
    union { float f; unsigned int u; } v; v.f = f;
    unsigned int r = v.u + 0x7fffu + ((v.u >> 16) & 1u);
    return (unsigned short)(r >> 16);
}

// async global->LDS, 16 B per lane. LDS dest is wave-uniform base + lane*16.
__device__ __forceinline__ void gload_lds16(const void* g, void* l) {
    __builtin_amdgcn_global_load_lds(
        (__attribute__((address_space(1))) void*)g,
        (__attribute__((address_space(3))) void*)l,
        16, 0, 0);
}

#define FENCE() asm volatile("" ::: "memory")
#define BARF()  do { FENCE(); __builtin_amdgcn_s_barrier(); FENCE(); } while (0)

// ---------------- pre-pass 1: input fp32 -> bf16 ----------------
__global__ __launch_bounds__(256) void cvt_a_kernel(
    const float* __restrict__ in, unsigned short* __restrict__ out)
{
    size_t i = (size_t)blockIdx.x * 256 + threadIdx.x;   // 8 elems / thread
    const float4* p = (const float4*)in;
    float4 x = p[2 * i], y = p[2 * i + 1];
    union { unsigned short h[8]; uint4 v; } u;
    u.h[0] = f2bf(x.x); u.h[1] = f2bf(x.y); u.h[2] = f2bf(x.z); u.h[3] = f2bf(x.w);
    u.h[4] = f2bf(y.x); u.h[5] = f2bf(y.y); u.h[6] = f2bf(y.z); u.h[7] = f2bf(y.w);
    ((uint4*)out)[i] = u.v;
}

// ---------------- pre-pass 2: dequant int4 codes -> bf16 [N,K] ----------------
__global__ __launch_bounds__(256) void dq_w_kernel(
    const int* __restrict__ w, const float* __restrict__ snz,
    unsigned short* __restrict__ out)
{
    size_t t = (size_t)blockIdx.x * 256 + threadIdx.x;   // 8 codes / thread
    int kc = (int)(t & (KK / 8 - 1));                    // K/8 = 512
    int n  = (int)(t >> 9);
    int g  = kc >> 2;                                    // 32 codes per group
    float2 sz = ((const float2*)snz)[(size_t)g * NN + n];  // {scale, zero}
    const int4* wp = (const int4*)w;
    int4 q0 = wp[2 * t], q1 = wp[2 * t + 1];
    union { unsigned short h[8]; uint4 v; } u;
    u.h[0] = f2bf((float)(q0.x - 8) * sz.x + sz.y);
    u.h[1] = f2bf((float)(q0.y - 8) * sz.x + sz.y);
    u.h[2] = f2bf((float)(q0.z - 8) * sz.x + sz.y);
    u.h[3] = f2bf((float)(q0.w - 8) * sz.x + sz.y);
    u.h[4] = f2bf((float)(q1.x - 8) * sz.x + sz.y);
    u.h[5] = f2bf((float)(q1.y - 8) * sz.x + sz.y);
    u.h[6] = f2bf((float)(q1.z - 8) * sz.x + sz.y);
    u.h[7] = f2bf((float)(q1.w - 8) * sz.x + sz.y);
    ((uint4*)out)[t] = u.v;
}

// ================= 256x256 GEMM, 32x32x16 MFMA, single-gate =================
// C[M,N] = A[M,K](bf16) * W[N,K](bf16)^T + bias, fp32 out.
// 8 waves (2M x 4N), wave output 128x64 = 4x2 blocks of 32x32, acc = 8 x f32x16.
// LDS 160 KiB: A TRIPLE-buffered (3 x 32 KiB @ 0/32768/65536),
//              B double-buffered  (2 x 32 KiB @ 98304/131072).
// 128-B rows, chunk-XOR swizzle (phys = logical ^ (row&7)) on write-src & read.
// K-tile 64 = 4 ksteps of 16. Per kstep: {4 A-reads + 2 B-reads, 8 MFMA}.
// Sync schedule = R6 (proven): stage B(t+1) at ks0 (overwrites B(t-1), whose
// reads completed before tile t-1's closing barrier), A(t+2) at ks2
// (overwrites A(t-1), same argument), ONE vmcnt+barrier gate per tile:
// vmcnt(4) leaves only A(t+2) in flight; vmcnt(0) once staging stops.
//
// 32x32x16 bf16 MFMA layouts:
//  A-frag: lane l holds A[row=l&31][k=(l>>5)*8 .. +8]  (bf16x8, analog of the
//          R1-verified 16x16x32 mapping row=l&15, k=(l>>4)*8)
//  C/D:    col = lane&31, row = (reg&3) + 8*(reg>>2) + 4*(lane>>5), reg 0..15
//          [measured: learn_hip m74/m101]
#define BM 256
#define BN 256
#define BK 64
#define TT (KK / BK)   // 64

__global__ __launch_bounds__(512, 2) void gemm256_kernel(
    const unsigned short* __restrict__ A,    // bf16 [M,K]
    const unsigned short* __restrict__ Bw,   // bf16 [N,K]
    const float* __restrict__ bias,          // [N]
    float* __restrict__ C)                   // fp32 [M,N]
{
    __shared__ char lds[163840];

    const int tid  = threadIdx.x;
    const int lane = tid & 63;
    const int wave = tid >> 6;            // 0..7
    const int wm   = wave >> 2;           // 0..1
    const int wn   = wave & 3;            // 0..3

    // XCD-aware swizzle (nwg = 32*48 = 1536, divisible by 8).
    const int NTN = NN / BN;              // 48
    const int nwg = (MM / BM) * NTN;      // 1536
    const int cpx = nwg >> 3;             // 192
    int wg = ((int)blockIdx.x & 7) * cpx + ((int)blockIdx.x >> 3);
    const int tm = wg / NTN;
    const int tn = wg - tm * NTN;

    f32x16 acc[8] = {};   // [mb*2 + nb]

    // ---- staging lane constants (R2-proven geometry) ----
    const int lrow = lane >> 3;
    const int lc   = (lane & 7) ^ lrow;
    const unsigned short* aSrc = A  + (size_t)(tm * BM + wave * 8 + lrow) * KK + lc * 8;
    const unsigned short* bSrc = Bw + (size_t)(tn * BN + wave * 8 + lrow) * KK + lc * 8;
    const int wblk = wave * 1024;

#define STAGE(srcBase, rowsOff, kOff, ldsPtr) do {                                          \
        gload_lds16((srcBase) + (size_t)(rowsOff) * KK + (kOff), (ldsPtr) + wblk);          \
        gload_lds16((srcBase) + (size_t)((rowsOff) + 64) * KK + (kOff), (ldsPtr) + 8192 + wblk); \
    } while (0)

    // ---- compute lane constants (32x32 fragment geometry) ----
    const int r7  = lane & 7;
    const int l31 = lane & 31;
    const int hi  = lane >> 5;                        // k-half selector
    // per-kstep phys chunk byte offsets: ((2*ks + hi) ^ (row&7)) * 16, row&7 == lane&7
    const int ck0 = ((0 + hi) ^ r7) << 4;
    const int ck1 = ((2 + hi) ^ r7) << 4;
    const int ck2 = ((4 + hi) ^ r7) << 4;
    const int ck3 = ((6 + hi) ^ r7) << 4;
    const int aoff = (wm * 128 + l31) * 128;          // A row byte offset (mb adds 4096)
    const int boff = (wn * 64  + l31) * 128;          // B row byte offset (nb adds 4096)

    char* const Ab0 = lds;                 // A buffers: 3 x 32 KiB
    char* const Bb0 = lds + 98304;         // B buffers: 2 x 32 KiB

    // ---- prologue: A(0)->Ab[0], B(0)->Bb[0], A(1)->Ab[1] (oldest first) ----
    STAGE(aSrc, 0,   0, Ab0);
    STAGE(aSrc, 128, 0, Ab0 + 16384);
    STAGE(bSrc, 0,   0, Bb0);
    STAGE(bSrc, 128, 0, Bb0 + 16384);
    STAGE(aSrc, 0,   BK, Ab0 + 32768);
    STAGE(aSrc, 128, BK, Ab0 + 32768 + 16384);
    asm volatile("s_waitcnt vmcnt(4)" ::: "memory");   // A(0),B(0) landed; A(1) in flight
    BARF();

    // one kstep: 4 A-reads + 2 B-reads (at chunk byte CK), 8 MFMA
#define KSTEP(CK) do {                                                            \
        bf16x8 a_[4], b_[2];                                                      \
        _Pragma("unroll")                                                         \
        for (int mb = 0; mb < 4; ++mb)                                            \
            a_[mb] = *(const bf16x8*)(Ab + aoff + mb * 4096 + (CK));              \
        b_[0] = *(const bf16x8*)(Bb + boff + 0 * 4096 + (CK));                    \
        b_[1] = *(const bf16x8*)(Bb + boff + 1 * 4096 + (CK));                    \
        __builtin_amdgcn_s_setprio(1);                                            \
        _Pragma("unroll")                                                         \
        for (int mb = 0; mb < 4; ++mb) {                                          \
            acc[mb * 2 + 0] = __builtin_amdgcn_mfma_f32_32x32x16_bf16(            \
                a_[mb], b_[0], acc[mb * 2 + 0], 0, 0, 0);                         \
            acc[mb * 2 + 1] = __builtin_amdgcn_mfma_f32_32x32x16_bf16(            \
                a_[mb], b_[1], acc[mb * 2 + 1], 0, 0, 0);                         \
        }                                                                         \
        __builtin_amdgcn_s_setprio(0);                                            \
    } while (0)

    int aR = 0;   // t % 3 (A read buffer)
#pragma unroll 1
    for (int t = 0; t < TT; ++t) {
        const char* Ab = Ab0 + (aR << 15);
        const char* Bb = Bb0 + ((t & 1) << 15);
        char* BstN = Bb0 + (((t & 1) ^ 1) << 15);        // B(t+1) dest
        const int aS = (aR == 0) ? 2 : aR - 1;           // (t+2) % 3
        char* AstN = Ab0 + (aS << 15);                   // A(t+2) dest
        const bool pfB = (t + 1 < TT);
        const bool pfA = (t + 2 < TT);
        const int kB = (t + 1) * BK;
        const int kA = (t + 2) * BK;

        // ---- ks0: stage B(t+1) ----
        {
            bf16x8 a_[4], b_[2];
#pragma unroll
            for (int mb = 0; mb < 4; ++mb)
                a_[mb] = *(const bf16x8*)(Ab + aoff + mb * 4096 + ck0);
            b_[0] = *(const bf16x8*)(Bb + boff + 0 * 4096 + ck0);
            b_[1] = *(const bf16x8*)(Bb + boff + 1 * 4096 + ck0);
            if (pfB) {
                STAGE(bSrc, 0,   kB, BstN);
                STAGE(bSrc, 128, kB, BstN + 16384);
            }
            __builtin_amdgcn_s_setprio(1);
#pragma unroll
            for (int mb = 0; mb < 4; ++mb) {
                acc[mb * 2 + 0] = __builtin_amdgcn_mfma_f32_32x32x16_bf16(
                    a_[mb], b_[0], acc[mb * 2 + 0], 0, 0, 0);
                acc[mb * 2 + 1] = __builtin_amdgcn_mfma_f32_32x32x16_bf16(
                    a_[mb], b_[1], acc[mb * 2 + 1], 0, 0, 0);
            }
            __builtin_amdgcn_s_setprio(0);
        }

        // ---- ks1 ----
        KSTEP(ck1);

        // ---- ks2: stage A(t+2) ----
        {
            bf16x8 a_[4], b_[2];
#pragma unroll
            for (int mb = 0; mb < 4; ++mb)
                a_[mb] = *(const bf16x8*)(Ab + aoff + mb * 4096 + ck2);
            b_[0] = *(const bf16x8*)(Bb + boff + 0 * 4096 + ck2);
            b_[1] = *(const bf16x8*)(Bb + boff + 1 * 4096 + ck2);
            if (pfA) {
                STAGE(aSrc, 0,   kA, AstN);
                STAGE(aSrc, 128, kA, AstN + 16384);
            }
            __builtin_amdgcn_s_setprio(1);
#pragma unroll
            for (int mb = 0; mb < 4; ++mb) {
                acc[mb * 2 + 0] = __builtin_amdgcn_mfma_f32_32x32x16_bf16(
                    a_[mb], b_[0], acc[mb * 2 + 0], 0, 0, 0);
                acc[mb * 2 + 1] = __builtin_amdgcn_mfma_f32_32x32x16_bf16(
                    a_[mb], b_[1], acc[mb * 2 + 1], 0, 0, 0);
            }
            __builtin_amdgcn_s_setprio(0);
        }

        // ---- ks3 + single tile gate ----
        KSTEP(ck3);
        if (t < TT - 1) {
            if (pfA) { asm volatile("s_waitcnt vmcnt(4)" ::: "memory"); }
            else     { asm volatile("s_waitcnt vmcnt(0)" ::: "memory"); }
            BARF();   // tile gate: A(t+1),B(t+1) landed; tile-t reads consumed
        }
        aR = (aR == 2) ? 0 : aR + 1;
    }
#undef KSTEP
#undef STAGE

    // ---- epilogue: C/D col=lane&31, row=(reg&3)+8*(reg>>2)+4*hi; fuse bias ----
    const int crow0 = tm * BM + wm * 128 + 4 * hi;
    const int ccol0 = tn * BN + wn * 64 + l31;
    float bv[2] = { bias[ccol0], bias[ccol0 + 32] };
#pragma unroll
    for (int mb = 0; mb < 4; ++mb)
#pragma unroll
        for (int nb = 0; nb < 2; ++nb)
#pragma unroll
            for (int reg = 0; reg < 16; ++reg) {
                int row = crow0 + mb * 32 + (reg & 3) + 8 * (reg >> 2);
                C[(size_t)row * NN + ccol0 + nb * 32] = acc[mb * 2 + nb][reg] + bv[nb];
            }
}

// ================= fallback: fused 128x128 (R1, known-correct) =================
__global__ __launch_bounds__(256) void gemm_fused_kernel(
    const float* __restrict__ Af,
    const int* __restrict__ Wq,
    const float* __restrict__ snz,
    const float* __restrict__ bias,
    float* __restrict__ C)
{
    __shared__ alignas(16) unsigned short As[128 * 64];
    __shared__ alignas(16) unsigned short Bs[128 * 64];

    const int tid  = threadIdx.x;
    const int lane = tid & 63;
    const int wave = tid >> 6;

    const int NTN = NN / 128;
    const int nwg = (MM / 128) * NTN;
    const int cpx = nwg >> 3;
    int wg = ((int)blockIdx.x & 7) * cpx + ((int)blockIdx.x >> 3);
    const int tm = wg / NTN;
    const int tn = wg - tm * NTN;

    const int wm = wave >> 1, wn = wave & 1;

    f32x4 acc[4][4] = {};

    const int r7  = lane & 7;
    const int pc0 = (((lane >> 4)    ) ^ r7) * 16;
    const int pc1 = (((lane >> 4) + 4) ^ r7) * 16;
    const int arow = wm * 64 + (lane & 15);
    const int brow = wn * 64 + (lane & 15);
    const char* AsR = (const char*)As;
    const char* BsR = (const char*)Bs;

    const int frow = tid >> 1;
    const int fh   = tid & 1;
    const int frx  = frow & 7;

    for (int k0 = 0; k0 < KK; k0 += 64) {
        {
            const float* ap = Af + (size_t)(tm * 128 + frow) * KK + k0 + fh * 32;
#pragma unroll
            for (int c = 0; c < 4; ++c) {
                float4 x = ((const float4*)ap)[2 * c];
                float4 y = ((const float4*)ap)[2 * c + 1];
                union { unsigned short h[8]; uint4 v; } u;
                u.h[0] = f2bf(x.x); u.h[1] = f2bf(x.y); u.h[2] = f2bf(x.z); u.h[3] = f2bf(x.w);
                u.h[4] = f2bf(y.x); u.h[5] = f2bf(y.y); u.h[6] = f2bf(y.z); u.h[7] = f2bf(y.w);
                int lc2 = fh * 4 + c;
                *(uint4*)&As[frow * 64 + ((lc2 ^ frx) * 8)] = u.v;
            }
        }
        {
            const int nrow = tn * 128 + frow;
            const int* wp = Wq + (size_t)nrow * KK + k0 + fh * 32;
            float2 sz = ((const float2*)snz)[(size_t)((k0 >> 5) + fh) * NN + nrow];
#pragma unroll
            for (int c = 0; c < 4; ++c) {
                int4 q0 = ((const int4*)wp)[2 * c];
                int4 q1 = ((const int4*)wp)[2 * c + 1];
                union { unsigned short h[8]; uint4 v; } u;
                u.h[0] = f2bf((float)(q0.x - 8) * sz.x + sz.y);
                u.h[1] = f2bf((float)(q0.y - 8) * sz.x + sz.y);
                u.h[2] = f2bf((float)(q0.z - 8) * sz.x + sz.y);
                u.h[3] = f2bf((float)(q0.w - 8) * sz.x + sz.y);
                u.h[4] = f2bf((float)(q1.x - 8) * sz.x + sz.y);
                u.h[5] = f2bf((float)(q1.y - 8) * sz.x + sz.y);
                u.h[6] = f2bf((float)(q1.z - 8) * sz.x + sz.y);
                u.h[7] = f2bf((float)(q1.w - 8) * sz.x + sz.y);
                int lc2 = fh * 4 + c;
                *(uint4*)&Bs[frow * 64 + ((lc2 ^ frx) * 8)] = u.v;
            }
        }
        __syncthreads();
        {
            bf16x8 af[4], bfr[4];
#pragma unroll
            for (int x = 0; x < 4; ++x) {
                af[x]  = *(const bf16x8*)(AsR + (arow + x * 16) * 128 + pc0);
                bfr[x] = *(const bf16x8*)(BsR + (brow + x * 16) * 128 + pc0);
            }
#pragma unroll
            for (int mi = 0; mi < 4; ++mi)
#pragma unroll
                for (int ni = 0; ni < 4; ++ni)
                    acc[mi][ni] = __builtin_amdgcn_mfma_f32_16x16x32_bf16(
                        af[mi], bfr[ni], acc[mi][ni], 0, 0, 0);
        }
        {
            bf16x8 af[4], bfr[4];
#pragma unroll
            for (int x = 0; x < 4; ++x) {
                af[x]  = *(const bf16x8*)(AsR + (arow + x * 16) * 128 + pc1);
                bfr[x] = *(const bf16x8*)(BsR + (brow + x * 16) * 128 + pc1);
            }
#pragma unroll
            for (int mi = 0; mi < 4; ++mi)
#pragma unroll
                for (int ni = 0; ni < 4; ++ni)
                    acc[mi][ni] = __builtin_amdgcn_mfma_f32_16x16x32_bf16(
                        af[mi], bfr[ni], acc[mi][ni], 0, 0, 0);
        }
        __syncthreads();
    }

    const int crow = tm * 128 + wm * 64 + (lane >> 4) * 4;
    const int ccol = tn * 128 + wn * 64 + (lane & 15);
    float bv[4];
#pragma unroll
    for (int ni = 0; ni < 4; ++ni) bv[ni] = bias[ccol + ni * 16];
#pragma unroll
    for (int mi = 0; mi < 4; ++mi)
#pragma unroll
        for (int ni = 0; ni < 4; ++ni)
#pragma unroll
            for (int j = 0; j < 4; ++j)
                C[(size_t)(crow + mi * 16 + j) * NN + ccol + ni * 16] =
                    acc[mi][ni][j] + bv[ni];
}

extern "C" void kernel_launch(void* const* d_in, const int* in_sizes, int n_in,
                              void* d_out, int out_size, void* d_ws, size_t ws_size,
                              hipStream_t stream)
{
    const float* inA  = (const float*)d_in[0];   // [M,K] fp32
    const int*   Wq   = (const int*)d_in[1];     // [N,K] int codes
    const float* snz  = (const float*)d_in[2];   // [K/32,N,2] fp32
    const float* bias = (const float*)d_in[3];   // [N] fp32
    float* out = (float*)d_out;

    const size_t needA = (size_t)MM * KK * 2;
    const size_t needW = (size_t)NN * KK * 2;

    if (ws_size >= needA + needW) {
        unsigned short* Abf = (unsigned short*)d_ws;
        unsigned short* Wbf = (unsigned short*)((char*)d_ws + needA);
        cvt_a_kernel<<<(MM * KK / 8) / 256, 256, 0, stream>>>(inA, Abf);
        dq_w_kernel<<<(NN * KK / 8) / 256, 256, 0, stream>>>(Wq, snz, Wbf);
        gemm256_kernel<<<(MM / BM) * (NN / BN), 512, 0, stream>>>(Abf, Wbf, bias, out);
    } else {
        gemm_fused_kernel<<<(MM / 128) * (NN / 128), 256, 0, stream>>>(
            inA, Wq, snz, bias, out);
    }
}

// Round 8
// 788.987 us; speedup vs baseline: 1.0973x; 1.0973x over previous
//
#include <hip/hip_runtime.h>
#include <hip/hip_bf16.h>
#include <cstdint>
#include <cstddef>

// Problem constants (fixed by the harness problem instance).
#define MM 8192
#define KK 4096
#define NN 12288

typedef __bf16 bf16x8 __attribute__((ext_vector_type(8)));
typedef float  f32x4  __attribute__((ext_vector_type(4)));

// fp32 -> bf16 round-to-nearest-even (finite inputs).
__device__ __forceinline__ unsigned short f2bf(float f) {
    union { float f; unsigned int u; } v; v.f = f;
    unsigned int r = v.u + 0x7fffu + ((v.u >> 16) & 1u);
    return (unsigned short)(r >> 16);
}

// async global->LDS, 16 B per lane. LDS dest is wave-uniform base + lane*16.
__device__ __forceinline__ void gload_lds16(const void* g, void* l) {
    __builtin_amdgcn_global_load_lds(
        (__attribute__((address_space(1))) void*)g,
        (__attribute__((address_space(3))) void*)l,
        16, 0, 0);
}

#define FENCE() asm volatile("" ::: "memory")
#define BARF()  do { FENCE(); __builtin_amdgcn_s_barrier(); FENCE(); } while (0)

// ---------------- pre-pass 1: input fp32 -> bf16 ----------------
__global__ __launch_bounds__(256) void cvt_a_kernel(
    const float* __restrict__ in, unsigned short* __restrict__ out)
{
    size_t i = (size_t)blockIdx.x * 256 + threadIdx.x;   // 8 elems / thread
    const float4* p = (const float4*)in;
    float4 x = p[2 * i], y = p[2 * i + 1];
    union { unsigned short h[8]; uint4 v; } u;
    u.h[0] = f2bf(x.x); u.h[1] = f2bf(x.y); u.h[2] = f2bf(x.z); u.h[3] = f2bf(x.w);
    u.h[4] = f2bf(y.x); u.h[5] = f2bf(y.y); u.h[6] = f2bf(y.z); u.h[7] = f2bf(y.w);
    ((uint4*)out)[i] = u.v;
}

// ---------------- pre-pass 2: dequant int4 codes -> bf16 [N,K] ----------------
__global__ __launch_bounds__(256) void dq_w_kernel(
    const int* __restrict__ w, const float* __restrict__ snz,
    unsigned short* __restrict__ out)
{
    size_t t = (size_t)blockIdx.x * 256 + threadIdx.x;   // 8 codes / thread
    int kc = (int)(t & (KK / 8 - 1));                    // K/8 = 512
    int n  = (int)(t >> 9);
    int g  = kc >> 2;                                    // 32 codes per group
    float2 sz = ((const float2*)snz)[(size_t)g * NN + n];  // {scale, zero}
    const int4* wp = (const int4*)w;
    int4 q0 = wp[2 * t], q1 = wp[2 * t + 1];
    union { unsigned short h[8]; uint4 v; } u;
    u.h[0] = f2bf((float)(q0.x - 8) * sz.x + sz.y);
    u.h[1] = f2bf((float)(q0.y - 8) * sz.x + sz.y);
    u.h[2] = f2bf((float)(q0.z - 8) * sz.x + sz.y);
    u.h[3] = f2bf((float)(q0.w - 8) * sz.x + sz.y);
    u.h[4] = f2bf((float)(q1.x - 8) * sz.x + sz.y);
    u.h[5] = f2bf((float)(q1.y - 8) * sz.x + sz.y);
    u.h[6] = f2bf((float)(q1.z - 8) * sz.x + sz.y);
    u.h[7] = f2bf((float)(q1.w - 8) * sz.x + sz.y);
    ((uint4*)out)[t] = u.v;
}

// ======= 256x256 GEMM, 16x16x32 MFMA, single-gate + 1-cluster SW pipeline =======
// C[M,N] = A[M,K](bf16) * W[N,K](bf16)^T + bias, fp32 out.
// 8 waves (2M x 4N), wave output 128x64, acc[8][4] f32x4 (AGPR).
// LDS 160 KiB: A TRIPLE-buffered (3 x 32 KiB @ 0/32768/65536),
//              B double-buffered  (2 x 32 KiB @ 98304/131072).
// 128-B rows, chunk-XOR swizzle (phys = logical ^ (row&7)) on write-src & read
// (R1-R6 proven: 0 bank conflicts; R7's 32x32 variant conflicted - reverted).
//
// Sync = R6 (proven): stage B(t+1) in c1, A(t+2)->Abuf[(t+2)%3] in c3
// (each overwrites data last read in tile t-1, drained by t-1's closing
// barrier), ONE vmcnt+barrier gate per tile (vmcnt(4) leaves A(t+2) in
// flight; vmcnt(0) once staging stops).
//
// NEW (R8): hand software-pipeline ds_reads one cluster ahead so each
// cluster's MFMAs consume frags read a cluster earlier (~260 cy of MFMA
// covers the ~120 cy LDS latency). R6 measured ~47% of peak = 2x per-wave
// serial time => waves were lockstep read-then-MFMA; this breaks the
// intra-wave read->MFMA dependency. setprio(1/0) pins the order.
//   head: preload a0[8], b00, b01
//   c1: issue b02,b03; stage B(t+1);  MFMA a0 x {b00,b01}
//   c2: issue a1[8], b10, b11;        MFMA a0 x {b02,b03}
//   c3: issue b12,b13; stage A(t+2);  MFMA a1 x {b10,b11}
//   c4:                               MFMA a1 x {b12,b13}
//   gate: vmcnt(4|0); barrier
#define BM 256
#define BN 256
#define BK 64
#define TT (KK / BK)   // 64

__global__ __launch_bounds__(512, 2) void gemm256_kernel(
    const unsigned short* __restrict__ A,    // bf16 [M,K]
    const unsigned short* __restrict__ Bw,   // bf16 [N,K]
    const float* __restrict__ bias,          // [N]
    float* __restrict__ C)                   // fp32 [M,N]
{
    __shared__ char lds[163840];

    const int tid  = threadIdx.x;
    const int lane = tid & 63;
    const int wave = tid >> 6;            // 0..7
    const int wm   = wave >> 2;           // 0..1
    const int wn   = wave & 3;            // 0..3

    // XCD-aware swizzle (nwg = 32*48 = 1536, divisible by 8).
    const int NTN = NN / BN;              // 48
    const int nwg = (MM / BM) * NTN;      // 1536
    const int cpx = nwg >> 3;             // 192
    int wg = ((int)blockIdx.x & 7) * cpx + ((int)blockIdx.x >> 3);
    const int tm = wg / NTN;
    const int tn = wg - tm * NTN;

    f32x4 acc[8][4] = {};

    // ---- staging lane constants (R2-proven geometry) ----
    const int lrow = lane >> 3;
    const int lc   = (lane & 7) ^ lrow;
    const unsigned short* aSrc = A  + (size_t)(tm * BM + wave * 8 + lrow) * KK + lc * 8;
    const unsigned short* bSrc = Bw + (size_t)(tn * BN + wave * 8 + lrow) * KK + lc * 8;
    const int wblk = wave * 1024;

#define STAGE(srcBase, rowsOff, kOff, ldsPtr) do {                                          \
        gload_lds16((srcBase) + (size_t)(rowsOff) * KK + (kOff), (ldsPtr) + wblk);          \
        gload_lds16((srcBase) + (size_t)((rowsOff) + 64) * KK + (kOff), (ldsPtr) + 8192 + wblk); \
    } while (0)

    // ---- compute lane constants (R2-proven geometry) ----
    const int r7  = lane & 7;
    const int l15 = lane & 15;
    const int c0  = (((lane >> 4)    ) ^ r7) * 16;   // kk0 phys chunk byte
    const int c1  = (((lane >> 4) + 4) ^ r7) * 16;   // kk1 phys chunk byte
    const int aoff = (wm * 128 + l15) * 128;         // A row byte offset (mf adds 2048)
    const int boff = (wn * 64  + l15) * 128;         // B row byte offset (nf adds 2048)

    char* const Ab0 = lds;                 // A buffers: 3 x 32 KiB
    char* const Bb0 = lds + 98304;         // B buffers: 2 x 32 KiB

    // ---- prologue: A(0)->Ab[0], B(0)->Bb[0], A(1)->Ab[1] (oldest first) ----
    STAGE(aSrc, 0,   0, Ab0);
    STAGE(aSrc, 128, 0, Ab0 + 16384);
    STAGE(bSrc, 0,   0, Bb0);
    STAGE(bSrc, 128, 0, Bb0 + 16384);
    STAGE(aSrc, 0,   BK, Ab0 + 32768);
    STAGE(aSrc, 128, BK, Ab0 + 32768 + 16384);
    asm volatile("s_waitcnt vmcnt(4)" ::: "memory");   // A(0),B(0) landed; A(1) in flight
    BARF();

#define MFMA8(AARR, BREG, NF)                                                     \
    _Pragma("unroll")                                                             \
    for (int mf = 0; mf < 8; ++mf)                                                \
        acc[mf][NF] = __builtin_amdgcn_mfma_f32_16x16x32_bf16(                    \
            AARR[mf], BREG, acc[mf][NF], 0, 0, 0);

    int aR = 0;   // t % 3 (A read buffer)
#pragma unroll 1
    for (int t = 0; t < TT; ++t) {
        const char* Ab = Ab0 + (aR << 15);
        const char* Bb = Bb0 + ((t & 1) << 15);
        char* BstN = Bb0 + (((t & 1) ^ 1) << 15);        // B(t+1) dest
        const int aS = (aR == 0) ? 2 : aR - 1;           // (t+2) % 3
        char* AstN = Ab0 + (aS << 15);                   // A(t+2) dest
        const bool pfB = (t + 1 < TT);
        const bool pfA = (t + 2 < TT);
        const int kB = (t + 1) * BK;
        const int kA = (t + 2) * BK;

        // ---- head: preload c1 operands (a0[8], b00, b01) ----
        bf16x8 a0[8];
#pragma unroll
        for (int mf = 0; mf < 8; ++mf)
            a0[mf] = *(const bf16x8*)(Ab + aoff + mf * 2048 + c0);
        bf16x8 b00 = *(const bf16x8*)(Bb + boff + 0 * 2048 + c0);
        bf16x8 b01 = *(const bf16x8*)(Bb + boff + 1 * 2048 + c0);

        // ---- c1: issue b02,b03; stage B(t+1); MFMA a0 x {b00,b01} ----
        bf16x8 b02 = *(const bf16x8*)(Bb + boff + 2 * 2048 + c0);
        bf16x8 b03 = *(const bf16x8*)(Bb + boff + 3 * 2048 + c0);
        if (pfB) {
            STAGE(bSrc, 0,   kB, BstN);
            STAGE(bSrc, 128, kB, BstN + 16384);
        }
        __builtin_amdgcn_s_setprio(1);
        MFMA8(a0, b00, 0); MFMA8(a0, b01, 1);
        __builtin_amdgcn_s_setprio(0);

        // ---- c2: issue a1[8], b10, b11; MFMA a0 x {b02,b03} ----
        bf16x8 a1[8];
#pragma unroll
        for (int mf = 0; mf < 8; ++mf)
            a1[mf] = *(const bf16x8*)(Ab + aoff + mf * 2048 + c1);
        bf16x8 b10 = *(const bf16x8*)(Bb + boff + 0 * 2048 + c1);
        bf16x8 b11 = *(const bf16x8*)(Bb + boff + 1 * 2048 + c1);
        __builtin_amdgcn_s_setprio(1);
        MFMA8(a0, b02, 2); MFMA8(a0, b03, 3);
        __builtin_amdgcn_s_setprio(0);

        // ---- c3: issue b12,b13; stage A(t+2); MFMA a1 x {b10,b11} ----
        bf16x8 b12 = *(const bf16x8*)(Bb + boff + 2 * 2048 + c1);
        bf16x8 b13 = *(const bf16x8*)(Bb + boff + 3 * 2048 + c1);
        if (pfA) {
            STAGE(aSrc, 0,   kA, AstN);
            STAGE(aSrc, 128, kA, AstN + 16384);
        }
        __builtin_amdgcn_s_setprio(1);
        MFMA8(a1, b10, 0); MFMA8(a1, b11, 1);
        __builtin_amdgcn_s_setprio(0);

        // ---- c4: MFMA a1 x {b12,b13}; single tile gate ----
        __builtin_amdgcn_s_setprio(1);
        MFMA8(a1, b12, 2); MFMA8(a1, b13, 3);
        __builtin_amdgcn_s_setprio(0);
        if (t < TT - 1) {
            if (pfA) { asm volatile("s_waitcnt vmcnt(4)" ::: "memory"); }
            else     { asm volatile("s_waitcnt vmcnt(0)" ::: "memory"); }
            BARF();   // tile gate: A(t+1),B(t+1) landed; tile-t reads consumed
        }
        aR = (aR == 2) ? 0 : aR + 1;
    }
#undef MFMA8
#undef STAGE

    // ---- epilogue: C/D layout col=lane&15, row=(lane>>4)*4+j; fuse bias ----
    const int crow = tm * BM + wm * 128 + (lane >> 4) * 4;
    const int ccol = tn * BN + wn * 64 + l15;
    float bv[4];
#pragma unroll
    for (int nf = 0; nf < 4; ++nf) bv[nf] = bias[ccol + nf * 16];
#pragma unroll
    for (int mf = 0; mf < 8; ++mf)
#pragma unroll
        for (int nf = 0; nf < 4; ++nf)
#pragma unroll
            for (int j = 0; j < 4; ++j)
                C[(size_t)(crow + mf * 16 + j) * NN + ccol + nf * 16] =
                    acc[mf][nf][j] + bv[nf];
}

// ================= fallback: fused 128x128 (R1, known-correct) =================
__global__ __launch_bounds__(256) void gemm_fused_kernel(
    const float* __restrict__ Af,
    const int* __restrict__ Wq,
    const float* __restrict__ snz,
    const float* __restrict__ bias,
    float* __restrict__ C)
{
    __shared__ alignas(16) unsigned short As[128 * 64];
    __shared__ alignas(16) unsigned short Bs[128 * 64];

    const int tid  = threadIdx.x;
    const int lane = tid & 63;
    const int wave = tid >> 6;

    const int NTN = NN / 128;
    const int nwg = (MM / 128) * NTN;
    const int cpx = nwg >> 3;
    int wg = ((int)blockIdx.x & 7) * cpx + ((int)blockIdx.x >> 3);
    const int tm = wg / NTN;
    const int tn = wg - tm * NTN;

    const int wm = wave >> 1, wn = wave & 1;

    f32x4 acc[4][4] = {};

    const int r7  = lane & 7;
    const int pc0 = (((lane >> 4)    ) ^ r7) * 16;
    const int pc1 = (((lane >> 4) + 4) ^ r7) * 16;
    const int arow = wm * 64 + (lane & 15);
    const int brow = wn * 64 + (lane & 15);
    const char* AsR = (const char*)As;
    const char* BsR = (const char*)Bs;

    const int frow = tid >> 1;
    const int fh   = tid & 1;
    const int frx  = frow & 7;

    for (int k0 = 0; k0 < KK; k0 += 64) {
        {
            const float* ap = Af + (size_t)(tm * 128 + frow) * KK + k0 + fh * 32;
#pragma unroll
            for (int c = 0; c < 4; ++c) {
                float4 x = ((const float4*)ap)[2 * c];
                float4 y = ((const float4*)ap)[2 * c + 1];
                union { unsigned short h[8]; uint4 v; } u;
                u.h[0] = f2bf(x.x); u.h[1] = f2bf(x.y); u.h[2] = f2bf(x.z); u.h[3] = f2bf(x.w);
                u.h[4] = f2bf(y.x); u.h[5] = f2bf(y.y); u.h[6] = f2bf(y.z); u.h[7] = f2bf(y.w);
                int lc2 = fh * 4 + c;
                *(uint4*)&As[frow * 64 + ((lc2 ^ frx) * 8)] = u.v;
            }
        }
        {
            const int nrow = tn * 128 + frow;
            const int* wp = Wq + (size_t)nrow * KK + k0 + fh * 32;
            float2 sz = ((const float2*)snz)[(size_t)((k0 >> 5) + fh) * NN + nrow];
#pragma unroll
            for (int c = 0; c < 4; ++c) {
                int4 q0 = ((const int4*)wp)[2 * c];
                int4 q1 = ((const int4*)wp)[2 * c + 1];
                union { unsigned short h[8]; uint4 v; } u;
                u.h[0] = f2bf((float)(q0.x - 8) * sz.x + sz.y);
                u.h[1] = f2bf((float)(q0.y - 8) * sz.x + sz.y);
                u.h[2] = f2bf((float)(q0.z - 8) * sz.x + sz.y);
                u.h[3] = f2bf((float)(q0.w - 8) * sz.x + sz.y);
                u.h[4] = f2bf((float)(q1.x - 8) * sz.x + sz.y);
                u.h[5] = f2bf((float)(q1.y - 8) * sz.x + sz.y);
                u.h[6] = f2bf((float)(q1.z - 8) * sz.x + sz.y);
                u.h[7] = f2bf((float)(q1.w - 8) * sz.x + sz.y);
                int lc2 = fh * 4 + c;
                *(uint4*)&Bs[frow * 64 + ((lc2 ^ frx) * 8)] = u.v;
            }
        }
        __syncthreads();
        {
            bf16x8 af[4], bfr[4];
#pragma unroll
            for (int x = 0; x < 4; ++x) {
                af[x]  = *(const bf16x8*)(AsR + (arow + x * 16) * 128 + pc0);
                bfr[x] = *(const bf16x8*)(BsR + (brow + x * 16) * 128 + pc0);
            }
#pragma unroll
            for (int mi = 0; mi < 4; ++mi)
#pragma unroll
                for (int ni = 0; ni < 4; ++ni)
                    acc[mi][ni] = __builtin_amdgcn_mfma_f32_16x16x32_bf16(
                        af[mi], bfr[ni], acc[mi][ni], 0, 0, 0);
        }
        {
            bf16x8 af[4], bfr[4];
#pragma unroll
            for (int x = 0; x < 4; ++x) {
                af[x]  = *(const bf16x8*)(AsR + (arow + x * 16) * 128 + pc1);
                bfr[x] = *(const bf16x8*)(BsR + (brow + x * 16) * 128 + pc1);
            }
#pragma unroll
            for (int mi = 0; mi < 4; ++mi)
#pragma unroll
                for (int ni = 0; ni < 4; ++ni)
                    acc[mi][ni] = __builtin_amdgcn_mfma_f32_16x16x32_bf16(
                        af[mi], bfr[ni], acc[mi][ni], 0, 0, 0);
        }
        __syncthreads();
    }

    const int crow = tm * 128 + wm * 64 + (lane >> 4) * 4;
    const int ccol = tn * 128 + wn * 64 + (lane & 15);
    float bv[4];
#pragma unroll
    for (int ni = 0; ni < 4; ++ni) bv[ni] = bias[ccol + ni * 16];
#pragma unroll
    for (int mi = 0; mi < 4; ++mi)
#pragma unroll
        for (int ni = 0; ni < 4; ++ni)
#pragma unroll
            for (int j = 0; j < 4; ++j)
                C[(size_t)(crow + mi * 16 + j) * NN + ccol + ni * 16] =
                    acc[mi][ni][j] + bv[ni];
}

extern "C" void kernel_launch(void* const* d_in, const int* in_sizes, int n_in,
                              void* d_out, int out_size, void* d_ws, size_t ws_size,
                              hipStream_t stream)
{
    const float* inA  = (const float*)d_in[0];   // [M,K] fp32
    const int*   Wq   = (const int*)d_in[1];     // [N,K] int codes
    const float* snz  = (const float*)d_in[2];   // [K/32,N,2] fp32
    const float* bias = (const float*)d_in[3];   // [N] fp32
    float* out = (float*)d_out;

    const size_t needA = (size_t)MM * KK * 2;
    const size_t needW = (size_t)NN * KK * 2;

    if (ws_size >= needA + needW) {
        unsigned short* Abf = (unsigned short*)d_ws;
        unsigned short* Wbf = (unsigned short*)((char*)d_ws + needA);
        cvt_a_kernel<<<(MM * KK / 8) / 256, 256, 0, stream>>>(inA, Abf);
        dq_w_kernel<<<(NN * KK / 8) / 256, 256, 0, stream>>>(Wq, snz, Wbf);
        gemm256_kernel<<<(MM / BM) * (NN / BN), 512, 0, stream>>>(Abf, Wbf, bias, out);
    } else {
        gemm_fused_kernel<<<(MM / 128) * (NN / 128), 256, 0, stream>>>(
            inA, Wq, snz, bias, out);
    }
}